// Round 5
// baseline (198.022 us; speedup 1.0000x reference)
//
#include <hip/hip_runtime.h>

typedef unsigned short u16;
typedef unsigned int u32;
typedef float v4f __attribute__((ext_vector_type(4)));
typedef __bf16 bf16x8 __attribute__((ext_vector_type(8)));

#define BATCH 8
#define CDIM 768
#define NHEAD 12
#define DH 64
#define NSEQ 1024
#define SCL 0.18033688011112042f

__device__ __forceinline__ u16 f2bf(float f) {
  u32 u = __builtin_bit_cast(u32, f);
  u += 0x7fffu + ((u >> 16) & 1u);   // RNE
  return (u16)(u >> 16);
}

__device__ __forceinline__ u16 b16(float f) {
  return (u16)((__builtin_bit_cast(u32, f) + 0x8000u) >> 16);
}

__device__ __forceinline__ u32 pkbf(float hi, float lo) {
  u32 a = __builtin_bit_cast(u32, hi) + 0x8000u;
  u32 b = __builtin_bit_cast(u32, lo) + 0x8000u;
  return __builtin_amdgcn_perm(a, b, 0x07060302u);  // {a[31:16], b[31:16]}
}

__device__ __forceinline__ v4f mfma16(bf16x8 a, bf16x8 b, v4f c) {
  return __builtin_amdgcn_mfma_f32_16x16x32_bf16(a, b, c, 0, 0, 0);
}

__device__ __forceinline__ void gload16(const u16* g, u16* l) {
  __builtin_amdgcn_global_load_lds(
      (const __attribute__((address_space(1))) void*)g,
      (__attribute__((address_space(3))) void*)l, 16, 0, 0);
}

// ------------- kernel: fused prep --------------------------------------
__global__ __launch_bounds__(256) void k_prep(const float* __restrict__ x,
                                              const float* __restrict__ wq,
                                              const float* __restrict__ wp,
                                              u16* __restrict__ xT,
                                              u16* __restrict__ wqb,
                                              u16* __restrict__ wpb) {
  __shared__ u16 Ts[64][72];
  int bid = blockIdx.x;
  int t = threadIdx.x;
  if (bid < 2304) {
    bool isQ = bid < 1728;
    const float* s = isQ ? wq : wp;
    u16* d = isQ ? wqb : wpb;
    int i = (isQ ? bid : bid - 1728) * 256 + t;
    float4 v = ((const float4*)s)[i];
    u32 lo = (u32)f2bf(v.x) | ((u32)f2bf(v.y) << 16);
    u32 hi = (u32)f2bf(v.z) | ((u32)f2bf(v.w) << 16);
    ((uint2*)d)[i] = uint2{lo, hi};
    return;
  }
  int id = bid - 2304;
  int p0 = (id & 15) * 64; id >>= 4;
  int c0 = (id % 12) * 64; int b = id / 12;
  int cr = t >> 4;
  int p4 = (t & 15) * 4;
  const float* src = x + ((size_t)b * CDIM + c0) * NSEQ + p0;
#pragma unroll
  for (int i = 0; i < 4; ++i) {
    int c = cr + i * 16;
    float4 v = *(const float4*)&src[(size_t)c * NSEQ + p4];
    Ts[p4 + 0][c] = f2bf(v.x);
    Ts[p4 + 1][c] = f2bf(v.y);
    Ts[p4 + 2][c] = f2bf(v.z);
    Ts[p4 + 3][c] = f2bf(v.w);
  }
  __syncthreads();
  int p = t >> 2;
  int cq = t & 3;
  u16* dst = xT + ((size_t)b * NSEQ + p0 + p) * CDIM + c0;
#pragma unroll
  for (int j = 0; j < 2; ++j) {
    int ch = cq + j * 4;
    *(int4*)&dst[ch * 8] = *(const int4*)&Ts[p][ch * 8];
  }
}

// ------------- 256x256 8-phase pipelined GEMM core (m201 template) -----
// 512 thr / 8 waves (2M x 4N), wave-tile 128x64, BK=64 (2 K-tiles/iter).
// LDS: 2 dbuf x [A 256x64 | B 256x64] split per k-half = 128 KB, 1 blk/CU.
// Layout: region(db, op, ks) = db*32768 + op*16384 + ks*8192 (u16), each
// region [256 rows][32 k], 64B row pitch, chunk-XOR swizzle:
// slot s of row r holds data chunk s ^ ((r>>1)&3), staged via pre-swizzled
// global source (LDS dest stays linear as global_load_lds requires).
// Schedule per iteration (tiles a=2i -> dbuf0, b=2i+1 -> dbuf1):
//   phase p: {ds_read 4A (+4B if mh==0); stage 1 half-tile (2 gload16);
//             vmcnt(4) at odd phases} barrier; lgkmcnt(0); 16 MFMA; barrier
//   stages: p0:A[b]k0 p1:B[b]k0 p2:A[b]k1 p3:B[b]k1
//           p4:A[a+2]k0 p5:B[a+2]k0 p6:A[a+2]k1 p7:B[a+2]k1
// vmcnt(4) at odd phase leaves exactly 2 half-tiles (4 loads) in flight and
// guarantees the half-tiles consumed 1 phase later; never drains to 0
// mid-loop. Last iter: phases 4-7 stage nothing; phase-5 wait becomes
// vmcnt(0) (drains H[2],H[3] before phase 6).
#define NIT 6   // 768 / 128

#define STAGE(gp, db, isB, ks, kt) do {                                   \
    u16* Ld_ = sm + (db) * 32768 + (isB) * 16384 + (ks) * 8192 + ldw;     \
    const u16* Gp_ = (gp) + (size_t)(kt) * 64 + (ks) * 32;                \
    gload16(Gp_, Ld_);                                                    \
    gload16(Gp_ + (size_t)128 * CDIM, Ld_ + 4096);                        \
  } while (0)

#define PHASE(db, ks, mh, ...) do {                                       \
    const u16* Ab_ = sm + (db) * 32768 + (ks) * 8192;                     \
    const u16* Bb_ = Ab_ + 16384;                                         \
    bf16x8 af[4];                                                         \
    _Pragma("unroll") for (int m = 0; m < 4; ++m)                         \
      af[m] = *(const bf16x8*)&Ab_[rAr + (mh) * 2048 + m * 512 + slot];   \
    if ((mh) == 0) {                                                      \
      _Pragma("unroll") for (int n = 0; n < 4; ++n)                       \
        bfr[n] = *(const bf16x8*)&Bb_[rBr + n * 512 + slot];              \
    }                                                                     \
    __VA_ARGS__;                                                          \
    asm volatile("s_barrier" ::: "memory");                               \
    asm volatile("s_waitcnt lgkmcnt(0)" ::: "memory");                    \
    __builtin_amdgcn_sched_barrier(0);                                    \
    __builtin_amdgcn_s_setprio(1);                                        \
    _Pragma("unroll") for (int m = 0; m < 4; ++m)                         \
      _Pragma("unroll") for (int n = 0; n < 4; ++n)                       \
        acc[(mh) * 4 + m][n] = mfma16(af[m], bfr[n], acc[(mh) * 4 + m][n]); \
    __builtin_amdgcn_s_setprio(0);                                        \
    __builtin_amdgcn_sched_barrier(0);                                    \
    asm volatile("s_barrier" ::: "memory");                               \
  } while (0)

#define VM4 asm volatile("s_waitcnt vmcnt(4)" ::: "memory")
#define VM0 asm volatile("s_waitcnt vmcnt(0)" ::: "memory")
#define FEN asm volatile("" ::: "memory")

__device__ __forceinline__ void gemm_core(const u16* __restrict__ Ag,
                                          const u16* __restrict__ Bg,
                                          u16* sm, v4f (&acc)[8][4]) {
  int t = threadIdx.x, lane = t & 63, wid = t >> 6;
  int ln = lane & 15, quad = lane >> 4;
  int wm = wid >> 2, wn = wid & 3;

  // staging: per gload16, thread t covers row t>>2 (0..127) of the 128-row
  // instr-slab, 16B chunk slot t&3 sourcing global chunk (t&3)^((t>>3)&3).
  const u16* As = Ag + (size_t)(t >> 2) * CDIM + ((t & 3) ^ ((t >> 3) & 3)) * 8;
  const u16* Bs = Bg + (size_t)(t >> 2) * CDIM + ((t & 3) ^ ((t >> 3) & 3)) * 8;
  int ldw = wid * 512;   // wave-uniform u16 offset inside a 4096-u16 slab

  // fragment reads: data chunk `quad` of row r is at slot quad^((r>>1)&3)
  int slot = (quad ^ ((ln >> 1) & 3)) * 8;
  int rAr = (wm * 128 + ln) * 32;
  int rBr = (wn * 64 + ln) * 32;

  bf16x8 bfr[4];

  // ---- prologue: stage tile 0's 4 half-tiles; wait first 2 ----
  STAGE(As, 0, 0, 0, 0); FEN;
  STAGE(Bs, 0, 1, 0, 0); FEN;
  STAGE(As, 0, 0, 1, 0); FEN;
  STAGE(Bs, 0, 1, 1, 0);
  VM4;   // A0k0,B0k0 resident; A0k1,B0k1 (4 loads) still in flight
  asm volatile("s_barrier" ::: "memory");

  for (int i = 0; i < NIT; ++i) {
    int b = 2 * i + 1, n2 = 2 * i + 2;
    bool nl = (i < NIT - 1);
    // tile a = 2i in dbuf0
    PHASE(0, 0, 0, STAGE(As, 1, 0, 0, b));
    PHASE(0, 0, 1, STAGE(Bs, 1, 1, 0, b); VM4);       // a-k1 resident
    PHASE(0, 1, 0, STAGE(As, 1, 0, 1, b));
    PHASE(0, 1, 1, STAGE(Bs, 1, 1, 1, b); VM4);       // b-k0 resident
    // tile b = 2i+1 in dbuf1
    PHASE(1, 0, 0, if (nl) STAGE(As, 0, 0, 0, n2));
    PHASE(1, 0, 1, if (nl) { STAGE(Bs, 0, 1, 0, n2); VM4; } else { VM0; });
    PHASE(1, 1, 0, if (nl) STAGE(As, 0, 0, 1, n2));
    PHASE(1, 1, 1, if (nl) { STAGE(Bs, 0, 1, 1, n2); VM4; });
  }
}

// ------------- kernel: QKV GEMM  D[o][p] = sum_c W[o][c] * xT[p][c] -----
// 288 blocks (9 oT x 32 p-panels). XCD swizzle: XCD x gets swz in
// [36x,36x+36) -> pIdx in [4x,4x+4) = exactly batch x (1.5 MB xT
// L2-resident) x all 9 o-tiles.
__global__ __launch_bounds__(512, 2) void k_gemm_qkv(const u16* __restrict__ Wb,
                                                     const u16* __restrict__ xT,
                                                     u16* __restrict__ qkT,
                                                     u16* __restrict__ vbuf) {
  __shared__ u16 sm[65536];   // 128 KB
  int bid = blockIdx.x;
  int swz = (bid & 7) * 36 + (bid >> 3);   // bijective: 288 % 8 == 0
  int oIdx = swz % 9, pIdx = swz / 9;
  int oT = oIdx * 256;
  int pG = pIdx * 256;                     // global p row (b*1024 + p)

  v4f acc[8][4] = {};
  gemm_core(Wb + (size_t)oT * CDIM, xT + (size_t)pG * CDIM, sm, acc);

  int t = threadIdx.x, lane = t & 63, wid = t >> 6;
  int ln = lane & 15, quad = lane >> 4;
  int wm = wid >> 2, wn = wid & 3;
  bool isV = oT >= 2 * CDIM;               // oIdx 6,7,8
#pragma unroll
  for (int m = 0; m < 8; ++m) {
#pragma unroll
    for (int n = 0; n < 4; ++n) {
      int ro = oT + wm * 128 + m * 16 + quad * 4;   // 4 consecutive o rows
      int cp = pG + wn * 64 + n * 16 + ln;
      int b = cp >> 10, p = cp & 1023;
      if (!isV) {
        u32 lo = (u32)f2bf(acc[m][n][0]) | ((u32)f2bf(acc[m][n][1]) << 16);
        u32 hi = (u32)f2bf(acc[m][n][2]) | ((u32)f2bf(acc[m][n][3]) << 16);
        *(uint2*)&qkT[((size_t)b * NSEQ + p) * 1536 + ro] = uint2{lo, hi};
      } else {
#pragma unroll
        for (int r = 0; r < 4; ++r)
          vbuf[((size_t)b * CDIM + (ro - 2 * CDIM + r)) * NSEQ + p] =
              f2bf(acc[m][n][r]);
      }
    }
  }
}

// ------------- kernel: flash attention ----------------------------------
// K/V slabs [64 rows][64 cols] (128 B pitch) with 8-chunk XOR swizzle via
// pre-swizzled global source; ds_read_b128 lands 2-way (free).
__global__ __launch_bounds__(256) void k_attn(const u16* __restrict__ qkT,
                                              const u16* __restrict__ vbuf,
                                              u16* __restrict__ attnT) {
  int id = blockIdx.x;
  int b = id & 7;
  int j = id >> 3;
  int h = j % 12;
  int nt0 = (j / 12) * 128;

  int t = threadIdx.x, lane = t & 63, wid = t >> 6;
  int ln = lane & 15, quad = lane >> 4;
  int nbase = nt0 + wid * 32;

  __shared__ u16 Ks[2][64 * 64];
  __shared__ u16 Vs[2][64 * 64];
  __shared__ u16 Pa[4][32 * 72];
  u16* myP = Pa[wid];

  const u16* qbase = qkT + ((size_t)b * NSEQ + nbase) * 1536 + h * DH;
  bf16x8 aq[2][2];
#pragma unroll
  for (int mt = 0; mt < 2; ++mt)
#pragma unroll
    for (int ks = 0; ks < 2; ++ks)
      aq[mt][ks] = *(const bf16x8*)&qbase[(size_t)(mt * 16 + ln) * 1536 + ks * 32 + quad * 8];

  bf16x8 ones;
#pragma unroll
  for (int i = 0; i < 8; ++i) ones[i] = __builtin_bit_cast(__bf16, (u16)0x3F80);

  v4f oacc[2][4] = {};
  v4f lacc[2] = {};

  int sr8 = lane >> 3;
  int sch = ((lane & 7) ^ sr8) * 8;
  const u16* kg0 = qkT + ((size_t)b * NSEQ + wid * 16 + sr8) * 1536 + CDIM + h * DH + sch;
  const u16* vg0 = vbuf + ((size_t)b * CDIM + h * DH + wid * 16 + sr8) * NSEQ + sch;
  int sK = (wid * 16) * 64;

  int sw0 = (quad ^ (ln & 7)) * 8;
  int sw1 = ((4 + quad) ^ (ln & 7)) * 8;

  gload16(kg0, &Ks[0][sK]);
  gload16(kg0 + (size_t)8 * 1536, &Ks[0][sK + 512]);
  gload16(vg0, &Vs[0][sK]);
  gload16(vg0 + 8 * NSEQ, &Vs[0][sK + 512]);
  __syncthreads();

  for (int s = 0; s < 16; ++s) {
    int cur = s & 1, nxt = cur ^ 1;
    if (s < 15) {
      size_t ko = (size_t)(s + 1) * 64 * 1536;
      int vo = (s + 1) * 64;
      gload16(kg0 + ko, &Ks[nxt][sK]);
      gload16(kg0 + ko + (size_t)8 * 1536, &Ks[nxt][sK + 512]);
      gload16(vg0 + vo, &Vs[nxt][sK]);
      gload16(vg0 + vo + 8 * NSEQ, &Vs[nxt][sK + 512]);
    }

#pragma unroll
    for (int ct = 0; ct < 4; ++ct) {
      bf16x8 kf0 = *(const bf16x8*)&Ks[cur][(ct * 16 + ln) * 64 + sw0];
      bf16x8 kf1 = *(const bf16x8*)&Ks[cur][(ct * 16 + ln) * 64 + sw1];
#pragma unroll
      for (int mt = 0; mt < 2; ++mt) {
        v4f sc = {};
        sc = mfma16(kf0, aq[mt][0], sc);
        sc = mfma16(kf1, aq[mt][1], sc);
        float p0 = __builtin_amdgcn_exp2f(sc[0] * SCL);
        float p1 = __builtin_amdgcn_exp2f(sc[1] * SCL);
        float p2 = __builtin_amdgcn_exp2f(sc[2] * SCL);
        float p3 = __builtin_amdgcn_exp2f(sc[3] * SCL);
        *(uint2*)&myP[(mt * 16 + ln) * 72 + ct * 16 + quad * 4] =
            uint2{pkbf(p1, p0), pkbf(p3, p2)};
      }
    }

    bf16x8 ap[2][2];
#pragma unroll
    for (int mt = 0; mt < 2; ++mt)
#pragma unroll
      for (int ks = 0; ks < 2; ++ks)
        ap[mt][ks] = *(const bf16x8*)&myP[(mt * 16 + ln) * 72 + ks * 32 + quad * 8];
#pragma unroll
    for (int mt = 0; mt < 2; ++mt) {
      lacc[mt] = mfma16(ap[mt][0], ones, lacc[mt]);
      lacc[mt] = mfma16(ap[mt][1], ones, lacc[mt]);
    }
#pragma unroll
    for (int nt = 0; nt < 4; ++nt) {
      bf16x8 vf0 = *(const bf16x8*)&Vs[cur][(nt * 16 + ln) * 64 + sw0];
      bf16x8 vf1 = *(const bf16x8*)&Vs[cur][(nt * 16 + ln) * 64 + sw1];
#pragma unroll
      for (int mt = 0; mt < 2; ++mt) {
        oacc[mt][nt] = mfma16(ap[mt][0], vf0, oacc[mt][nt]);
        oacc[mt][nt] = mfma16(ap[mt][1], vf1, oacc[mt][nt]);
      }
    }
    __syncthreads();
  }

#pragma unroll
  for (int mt = 0; mt < 2; ++mt) {
#pragma unroll
    for (int r = 0; r < 4; ++r) {
      float inv = 1.0f / lacc[mt][r];
      int n = nbase + mt * 16 + quad * 4 + r;
      u16* dst = attnT + ((size_t)b * NSEQ + n) * CDIM + h * DH;
#pragma unroll
      for (int nt = 0; nt < 4; ++nt)
        dst[nt * 16 + ln] = b16(oacc[mt][nt][r] * inv);
    }
  }
}

// ------------- kernel: proj GEMM ----------------------------------------
// 96 blocks (3 oT x 32 p-panels), single round; XCD swizzle -> each XCD
// owns one batch's attnT panel.
__global__ __launch_bounds__(512, 2) void k_gemm_proj(const u16* __restrict__ Wb,
                                                      const u16* __restrict__ aT,
                                                      float* __restrict__ out) {
  __shared__ u16 sm[65536];   // 128 KB
  int bid = blockIdx.x;
  int swz = (bid & 7) * 12 + (bid >> 3);   // bijective: 96 % 8 == 0
  int oIdx = swz % 3, pIdx = swz / 3;
  int oT = oIdx * 256;
  int pG = pIdx * 256;

  v4f acc[8][4] = {};
  gemm_core(Wb + (size_t)oT * CDIM, aT + (size_t)pG * CDIM, sm, acc);

  int t = threadIdx.x, lane = t & 63, wid = t >> 6;
  int ln = lane & 15, quad = lane >> 4;
  int wm = wid >> 2, wn = wid & 3;
#pragma unroll
  for (int m = 0; m < 8; ++m) {
#pragma unroll
    for (int n = 0; n < 4; ++n) {
      int ro = oT + wm * 128 + m * 16 + quad * 4;
      int cp = pG + wn * 64 + n * 16 + ln;
      int b = cp >> 10, p = cp & 1023;
#pragma unroll
      for (int r = 0; r < 4; ++r)
        out[((size_t)b * CDIM + ro + r) * NSEQ + p] = acc[m][n][r];
    }
  }
}

extern "C" void kernel_launch(void* const* d_in, const int* in_sizes, int n_in,
                              void* d_out, int out_size, void* d_ws, size_t ws_size,
                              hipStream_t stream) {
  const float* x = (const float*)d_in[0];
  const float* w_qkv = (const float*)d_in[1];
  const float* w_proj = (const float*)d_in[2];
  float* out = (float*)d_out;

  char* ws = (char*)d_ws;
  u16* wqkv_bf = (u16*)(ws);
  u16* wproj_bf = (u16*)(ws + 3538944);
  u16* xT = (u16*)(ws + 4718592);
  u16* vbuf = (u16*)(ws + 17301504);
  u16* qkT = (u16*)d_out;
  u16* attnT = xT;

  k_prep<<<dim3(3840), dim3(256), 0, stream>>>(x, w_qkv, w_proj, xT, wqkv_bf, wproj_bf);
  k_gemm_qkv<<<dim3(288), dim3(512), 0, stream>>>(wqkv_bf, xT, qkT, vbuf);
  k_attn<<<dim3(768), dim3(256), 0, stream>>>(qkT, vbuf, attnT);
  k_gemm_proj<<<dim3(96), dim3(512), 0, stream>>>(wproj_bf, attnT, out);
}